// Round 1
// baseline (1152.890 us; speedup 1.0000x reference)
//
#include <hip/hip_runtime.h>
#include <cstdint>
#include <cstddef>

typedef __attribute__((ext_vector_type(4))) int int32x4;

#define DEVI __device__ __forceinline__

constexpr int Bc = 8, Sc = 2048;
constexpr int M = Bc * Sc;        // 16384
constexpr int N = 11008;
constexpr int K = 4096;
constexpr int BM = 128, BN = 128, BK = 128;
constexpr int NT_N = N / BN;      // 86 (exact)
constexpr int NT_M = M / BM;      // 128 (exact)

DEVI void gload_lds16(const void* gsrc, void* ldst) {
  __builtin_amdgcn_global_load_lds(
      (const __attribute__((address_space(1))) unsigned int*)gsrc,
      (__attribute__((address_space(3))) unsigned int*)ldst,
      16, 0, 0);
}

// Repack weight (delivered as int32 per harness integer convention) -> int8.
__global__ __launch_bounds__(256) void pack_w_kernel(const int* __restrict__ w32,
                                                     signed char* __restrict__ w8) {
  const int idx = blockIdx.x * 256 + threadIdx.x;   // one int4 (4 values) each
  const int total4 = N * K / 4;
  if (idx < total4) {
    const int4 v = ((const int4*)w32)[idx];
    const int packed = (v.x & 255) | ((v.y & 255) << 8) |
                       ((v.z & 255) << 16) | ((v.w & 255) << 24);
    ((int*)w8)[idx] = packed;
  }
}

// Per-row symmetric int8 quantization of X (RNE), scale = amax/127 per row.
__global__ __launch_bounds__(256) void quant_x_kernel(const float* __restrict__ x,
                                                      signed char* __restrict__ xq,
                                                      float* __restrict__ sx) {
  const int row = blockIdx.x;       // M rows
  const int t = threadIdx.x;        // 256
  const float4* xr = (const float4*)(x + (size_t)row * K);
  float4 v[4];
  float amax = 0.f;
  #pragma unroll
  for (int c = 0; c < 4; ++c) {
    v[c] = xr[c * 256 + t];
    amax = fmaxf(amax, fmaxf(fmaxf(fabsf(v[c].x), fabsf(v[c].y)),
                             fmaxf(fabsf(v[c].z), fabsf(v[c].w))));
  }
  __shared__ float red[256];
  red[t] = amax;
  __syncthreads();
  #pragma unroll
  for (int s = 128; s >= 1; s >>= 1) {
    if (t < s) red[t] = fmaxf(red[t], red[t + s]);
    __syncthreads();
  }
  const float am = fmaxf(red[0], 1e-20f);
  const float inv = 127.f / am;
  if (t == 0) sx[row] = am * (1.f / 127.f);
  int* xq32 = (int*)(xq + (size_t)row * K);
  #pragma unroll
  for (int c = 0; c < 4; ++c) {
    int q0 = __float2int_rn(v[c].x * inv);
    int q1 = __float2int_rn(v[c].y * inv);
    int q2 = __float2int_rn(v[c].z * inv);
    int q3 = __float2int_rn(v[c].w * inv);
    q0 = min(127, max(-127, q0));
    q1 = min(127, max(-127, q1));
    q2 = min(127, max(-127, q2));
    q3 = min(127, max(-127, q3));
    xq32[c * 256 + t] = (q0 & 255) | ((q1 & 255) << 8) |
                        ((q2 & 255) << 16) | ((q3 & 255) << 24);
  }
}

// 128x128 tile int8 GEMM: C = Xq[M,K] * Wq[N,K]^T, dequant in epilogue.
// 4 waves, each owns a 64x64 output sub-tile (4x4 fragments of 16x16).
// BK=128 staged via global_load_lds (raw int8), XOR slot-swizzle (row&7)
// applied on the GLOBAL source side; ds_read_b128 applies the same XOR.
__global__ __launch_bounds__(256) void gemm_i8_kernel(const signed char* __restrict__ aq,
                                                      const signed char* __restrict__ wq,
                                                      const float* __restrict__ sx,
                                                      const float* __restrict__ sw,
                                                      float* __restrict__ out) {
  __shared__ __align__(16) signed char lsA[BM * BK];   // 16 KB
  __shared__ __align__(16) signed char lsB[BN * BK];   // 16 KB
  const int t = threadIdx.x;
  const int bid = blockIdx.x;
  const int mt = bid / NT_N;
  const int nt = bid % NT_N;
  const int m0 = mt * BM, n0 = nt * BN;
  const int wv = t >> 6;            // wave 0..3
  const int l = t & 63;
  const int wr = (wv >> 1) << 6;    // wave row offset: 0 or 64
  const int wc = (wv & 1) << 6;     // wave col offset: 0 or 64
  const int lrow = l & 15;
  const int lk = l >> 4;            // 0..3

  // Precompute staging sources (per 16B chunk) and wave-uniform LDS offsets.
  const signed char* aSrc[4];
  const signed char* bSrc[4];
  int ldsOff[4];
  #pragma unroll
  for (int c = 0; c < 4; ++c) {
    const int g = c * 256 + t;          // chunk id 0..1023
    const int row = g >> 3;             // 0..127
    const int slot = g & 7;             // 16B slot within 128B row
    const int sz = ((slot ^ (row & 7)) << 4);   // pre-swizzled global source
    aSrc[c] = aq + (size_t)(m0 + row) * K + sz;
    bSrc[c] = wq + (size_t)(n0 + row) * K + sz;
    ldsOff[c] = ((c * 256) + (t & ~63)) << 4;   // wave-uniform base
  }

  int32x4 acc[4][4] = {};

  for (int kt = 0; kt < K; kt += BK) {
    #pragma unroll
    for (int c = 0; c < 4; ++c) {
      gload_lds16(aSrc[c] + kt, lsA + ldsOff[c]);
      gload_lds16(bSrc[c] + kt, lsB + ldsOff[c]);
    }
    __syncthreads();   // drains vmcnt before barrier (compiler-inserted)
    #pragma unroll
    for (int ks = 0; ks < 2; ++ks) {
      int32x4 af[4], bf[4];
      const int ka = ((((ks << 2) | lk) ^ (lrow & 7)) << 4);  // swizzled k-slot byte
      #pragma unroll
      for (int i = 0; i < 4; ++i)
        af[i] = *(const int32x4*)(lsA + (wr + i * 16 + lrow) * BK + ka);
      #pragma unroll
      for (int j = 0; j < 4; ++j)
        bf[j] = *(const int32x4*)(lsB + (wc + j * 16 + lrow) * BK + ka);
      #pragma unroll
      for (int i = 0; i < 4; ++i) {
        #pragma unroll
        for (int j = 0; j < 4; ++j) {
          acc[i][j] = __builtin_amdgcn_mfma_i32_16x16x64_i8(af[i], bf[j], acc[i][j], 0, 0, 0);
        }
      }
    }
    __syncthreads();
  }

  // Epilogue: dequant + store fp32.  C/D map: col = lane&15, row = (lane>>4)*4 + reg.
  float swv[4];
  #pragma unroll
  for (int j = 0; j < 4; ++j) swv[j] = sw[n0 + wc + j * 16 + lrow];
  #pragma unroll
  for (int i = 0; i < 4; ++i) {
    #pragma unroll
    for (int r = 0; r < 4; ++r) {
      const int grow = m0 + wr + i * 16 + lk * 4 + r;
      const float sxv = sx[grow];
      float* orow = out + (size_t)grow * N + n0 + wc;
      #pragma unroll
      for (int j = 0; j < 4; ++j) {
        orow[j * 16 + lrow] = (float)acc[i][j][r] * sxv * swv[j];
      }
    }
  }
}

extern "C" void kernel_launch(void* const* d_in, const int* in_sizes, int n_in,
                              void* d_out, int out_size, void* d_ws, size_t ws_size,
                              hipStream_t stream) {
  const float* x = (const float*)d_in[0];
  const int* w32 = (const int*)d_in[1];       // int inputs arrive as int32
  const float* wscale = (const float*)d_in[2];
  float* out = (float*)d_out;

  // workspace layout: Xq[M*K] int8 | Wq[N*K] int8 | sx[M] fp32  (~107 MB)
  signed char* xq = (signed char*)d_ws;
  signed char* wq = xq + (size_t)M * K;
  float* sx = (float*)(wq + (size_t)N * K);

  pack_w_kernel<<<(N * K / 4 + 255) / 256, 256, 0, stream>>>(w32, wq);
  quant_x_kernel<<<M, 256, 0, stream>>>(x, xq, sx);
  gemm_i8_kernel<<<NT_M * NT_N, 256, 0, stream>>>(xq, wq, sx, wscale, out);
}

// Round 2
// 1050.245 us; speedup vs baseline: 1.0977x; 1.0977x over previous
//
#include <hip/hip_runtime.h>
#include <cstdint>
#include <cstddef>

typedef __attribute__((ext_vector_type(4))) int int32x4;
typedef __attribute__((ext_vector_type(16))) int int32x16;

#define DEVI __device__ __forceinline__

constexpr int M = 16384;
constexpr int N = 11008;
constexpr int K = 4096;
constexpr int BM = 256, BN = 256, BK = 64;   // BK in int8 elements (= bytes)
constexpr int NT_M = M / BM;                 // 64
constexpr int NT_N = N / BN;                 // 43
constexpr int NTILES = K / BK;               // 64
constexpr int NWG = NT_M * NT_N;             // 2752 = 8 * 344 (exact)
constexpr int TILE_BYTES = BM * BK;          // 16384 per tensor per buffer

DEVI void gload_lds16(const void* gsrc, void* ldst) {
  __builtin_amdgcn_global_load_lds(
      (const __attribute__((address_space(1))) unsigned int*)gsrc,
      (__attribute__((address_space(3))) unsigned int*)ldst,
      16, 0, 0);
}

// ---- weight repack: int32 (harness int convention) -> int8 ----
__global__ __launch_bounds__(256) void pack_w_kernel(const int* __restrict__ w32,
                                                     signed char* __restrict__ w8) {
  const int idx = blockIdx.x * 256 + threadIdx.x;
  const int total4 = N * K / 4;
  if (idx < total4) {
    const int4 v = ((const int4*)w32)[idx];
    ((int*)w8)[idx] = (v.x & 255) | ((v.y & 255) << 8) |
                      ((v.z & 255) << 16) | ((v.w & 255) << 24);
  }
}

// ---- per-row symmetric int8 quantization of X ----
__global__ __launch_bounds__(256) void quant_x_kernel(const float* __restrict__ x,
                                                      signed char* __restrict__ xq,
                                                      float* __restrict__ sx) {
  const int row = blockIdx.x;
  const int t = threadIdx.x;
  const float4* xr = (const float4*)(x + (size_t)row * K);
  float4 v[4];
  float amax = 0.f;
  #pragma unroll
  for (int c = 0; c < 4; ++c) {
    v[c] = xr[c * 256 + t];
    amax = fmaxf(amax, fmaxf(fmaxf(fabsf(v[c].x), fabsf(v[c].y)),
                             fmaxf(fabsf(v[c].z), fabsf(v[c].w))));
  }
  __shared__ float red[256];
  red[t] = amax;
  __syncthreads();
  #pragma unroll
  for (int s = 128; s >= 1; s >>= 1) {
    if (t < s) red[t] = fmaxf(red[t], red[t + s]);
    __syncthreads();
  }
  const float am = fmaxf(red[0], 1e-20f);
  const float inv = 127.f / am;
  if (t == 0) sx[row] = am * (1.f / 127.f);
  int* xq32 = (int*)(xq + (size_t)row * K);
  #pragma unroll
  for (int c = 0; c < 4; ++c) {
    int q0 = min(127, max(-127, __float2int_rn(v[c].x * inv)));
    int q1 = min(127, max(-127, __float2int_rn(v[c].y * inv)));
    int q2 = min(127, max(-127, __float2int_rn(v[c].z * inv)));
    int q3 = min(127, max(-127, __float2int_rn(v[c].w * inv)));
    xq32[c * 256 + t] = (q0 & 255) | ((q1 & 255) << 8) |
                        ((q2 & 255) << 16) | ((q3 & 255) << 24);
  }
}

// ---- 256x256 int8 GEMM, 4-deep LDS ring, counted vmcnt (never 0 in loop) ----
// LDS layout per tensor per buffer (k-plane-major, conflict-free b128 reads):
//   addr(row, kbyte) = (kbyte>>4)*4096 + row*16 + (kbyte&15)
// global_load_lds writes each 1 KB wave-chunk linearly; per-lane global source
// carries the permutation (rule: linear dest + permuted source).
__global__ __launch_bounds__(512, 2) void gemm_i8_kernel(const signed char* __restrict__ aq,
                                                         const signed char* __restrict__ wq,
                                                         const float* __restrict__ sx,
                                                         const float* __restrict__ sw,
                                                         float* __restrict__ out) {
  extern __shared__ signed char smem[];            // 131072 B
  signed char* lsA = smem;                          // 4 bufs x 16 KB
  signed char* lsB = smem + 4 * TILE_BYTES;         // 4 bufs x 16 KB

  const int tid = threadIdx.x;
  const int w = tid >> 6;          // wave 0..7
  const int l = tid & 63;

  // XCD-aware swizzle (bijective: 2752 % 8 == 0), then row-major tile map.
  const int bid = blockIdx.x;
  const int wg = (bid & 7) * (NWG / 8) + (bid >> 3);
  const int mt = wg / NT_N;
  const int nt = wg % NT_N;
  const int m0 = mt * BM, n0 = nt * BN;

  // Staging assignment: waves 0..3 stage A, waves 4..7 stage B.
  // chunk q = (w&3)*4 + c : plane s = q>>2, rowblock = q&3, row = (q&3)*64 + l.
  const bool stA = (w < 4);
  const signed char* src[4];
  int loff[4];
  #pragma unroll
  for (int c = 0; c < 4; ++c) {
    const int q = (w & 3) * 4 + c;
    const int row = (q & 3) * 64 + l;
    const int s = q >> 2;
    const signed char* base = stA ? (aq + (size_t)(m0 + row) * K)
                                  : (wq + (size_t)(n0 + row) * K);
    src[c] = base + s * 16;
    loff[c] = q * 1024;            // wave-uniform dest base; HW adds lane*16
  }

  auto STAGE = [&](int tile) {
    signed char* lbase = (stA ? lsA : lsB) + (tile & 3) * TILE_BYTES;
    const int koff = tile * BK;
    #pragma unroll
    for (int c = 0; c < 4; ++c)
      gload_lds16(src[c] + koff, lbase + loff[c]);
  };

  // Wave output: 128x64 at (wm*128, wn*64); 4x2 frags of 32x32.
  const int wm = w >> 2, wn = w & 3;
  const int aBase = (l >> 5) * 4096 + (wm * 128 + (l & 31)) * 16;
  const int bBase = (l >> 5) * 4096 + (wn * 64 + (l & 31)) * 16;

  int32x16 acc[4][2] = {};

  auto COMPUTE = [&](int tile) {
    const signed char* pA = lsA + (tile & 3) * TILE_BYTES;
    const signed char* pB = lsB + (tile & 3) * TILE_BYTES;
    int32x4 af[2][4], bf[2][2];
    #pragma unroll
    for (int ks = 0; ks < 2; ++ks) {
      #pragma unroll
      for (int j = 0; j < 2; ++j)
        bf[ks][j] = *(const int32x4*)(pB + bBase + ks * 8192 + j * 512);
      #pragma unroll
      for (int i = 0; i < 4; ++i)
        af[ks][i] = *(const int32x4*)(pA + aBase + ks * 8192 + i * 512);
    }
    __builtin_amdgcn_s_setprio(1);
    #pragma unroll
    for (int ks = 0; ks < 2; ++ks) {
      #pragma unroll
      for (int i = 0; i < 4; ++i) {
        #pragma unroll
        for (int j = 0; j < 2; ++j) {
          acc[i][j] = __builtin_amdgcn_mfma_i32_32x32x32_i8(af[ks][i], bf[ks][j],
                                                            acc[i][j], 0, 0, 0);
        }
      }
    }
    __builtin_amdgcn_s_setprio(0);
  };

  // Ring pipeline. Invariant at top-of-iter t barrier: tiles <= t retired for
  // ALL waves; tiles t+1,t+2 in flight (8 loads); buf[(t+3)%4] = buf[(t-1)%4]
  // is free (all waves finished reading t-1 before this barrier).
  STAGE(0); STAGE(1); STAGE(2);
  for (int t = 0; t <= NTILES - 4; ++t) {
    asm volatile("s_waitcnt vmcnt(8)\n\ts_barrier" ::: "memory");
    STAGE(t + 3);
    COMPUTE(t);
  }
  asm volatile("s_waitcnt vmcnt(8)\n\ts_barrier" ::: "memory");
  COMPUTE(NTILES - 3);
  asm volatile("s_waitcnt vmcnt(4)\n\ts_barrier" ::: "memory");
  COMPUTE(NTILES - 2);
  asm volatile("s_waitcnt vmcnt(0)\n\ts_barrier" ::: "memory");
  COMPUTE(NTILES - 1);

  // Epilogue: dequant + store.
  // 32x32 C/D map: col = lane&31, row = (r&3) + 8*(r>>2) + 4*(lane>>5).
  const int col = l & 31;
  const int rbase = (l >> 5) * 4;
  float swv[2];
  #pragma unroll
  for (int fj = 0; fj < 2; ++fj) swv[fj] = sw[n0 + wn * 64 + fj * 32 + col];
  #pragma unroll
  for (int fi = 0; fi < 4; ++fi) {
    #pragma unroll
    for (int r = 0; r < 16; ++r) {
      const int row = (r & 3) + 8 * (r >> 2) + rbase;
      const int grow = m0 + wm * 128 + fi * 32 + row;
      const float sxv = sx[grow];
      float* orow = out + (size_t)grow * N + n0 + wn * 64 + col;
      #pragma unroll
      for (int fj = 0; fj < 2; ++fj) {
        orow[fj * 32] = (float)acc[fi][fj][r] * sxv * swv[fj];
      }
    }
  }
}

extern "C" void kernel_launch(void* const* d_in, const int* in_sizes, int n_in,
                              void* d_out, int out_size, void* d_ws, size_t ws_size,
                              hipStream_t stream) {
  const float* x = (const float*)d_in[0];
  const int* w32 = (const int*)d_in[1];
  const float* wscale = (const float*)d_in[2];
  float* out = (float*)d_out;

  signed char* xq = (signed char*)d_ws;
  signed char* wq = xq + (size_t)M * K;
  float* sx = (float*)(wq + (size_t)N * K);

  pack_w_kernel<<<(N * K / 4 + 255) / 256, 256, 0, stream>>>(w32, wq);
  quant_x_kernel<<<M, 256, 0, stream>>>(x, xq, sx);
  gemm_i8_kernel<<<NWG, 512, 131072, stream>>>(xq, wq, sx, wscale, out);
}

// Round 3
// 1047.327 us; speedup vs baseline: 1.1008x; 1.0028x over previous
//
#include <hip/hip_runtime.h>
#include <cstdint>
#include <cstddef>

typedef __attribute__((ext_vector_type(4))) int int32x4;
typedef __attribute__((ext_vector_type(16))) int int32x16;

#define DEVI __device__ __forceinline__

constexpr int M = 16384;
constexpr int N = 11008;
constexpr int K = 4096;
constexpr int BM = 256, BN = 256, BK = 64;   // BK in int8 elements (= bytes)
constexpr int NT_M = M / BM;                 // 64
constexpr int NT_N = N / BN;                 // 43
constexpr int NTILES = K / BK;               // 64
constexpr int NWG = NT_M * NT_N;             // 2752 = 8 * 344 (exact)
constexpr int TILE_BYTES = BM * BK;          // 16384 per tensor per buffer

DEVI void gload_lds16(const void* gsrc, void* ldst) {
  __builtin_amdgcn_global_load_lds(
      (const __attribute__((address_space(1))) unsigned int*)gsrc,
      (__attribute__((address_space(3))) unsigned int*)ldst,
      16, 0, 0);
}

// ---- weight repack: int32 (harness int convention) -> int8 ----
__global__ __launch_bounds__(256) void pack_w_kernel(const int* __restrict__ w32,
                                                     signed char* __restrict__ w8) {
  const int idx = blockIdx.x * 256 + threadIdx.x;
  const int total4 = N * K / 4;
  if (idx < total4) {
    const int4 v = ((const int4*)w32)[idx];
    ((int*)w8)[idx] = (v.x & 255) | ((v.y & 255) << 8) |
                      ((v.z & 255) << 16) | ((v.w & 255) << 24);
  }
}

// ---- per-row symmetric int8 quantization of X ----
__global__ __launch_bounds__(256) void quant_x_kernel(const float* __restrict__ x,
                                                      signed char* __restrict__ xq,
                                                      float* __restrict__ sx) {
  const int row = blockIdx.x;
  const int t = threadIdx.x;
  const float4* xr = (const float4*)(x + (size_t)row * K);
  float4 v[4];
  float amax = 0.f;
  #pragma unroll
  for (int c = 0; c < 4; ++c) {
    v[c] = xr[c * 256 + t];
    amax = fmaxf(amax, fmaxf(fmaxf(fabsf(v[c].x), fabsf(v[c].y)),
                             fmaxf(fabsf(v[c].z), fabsf(v[c].w))));
  }
  __shared__ float red[256];
  red[t] = amax;
  __syncthreads();
  #pragma unroll
  for (int s = 128; s >= 1; s >>= 1) {
    if (t < s) red[t] = fmaxf(red[t], red[t + s]);
    __syncthreads();
  }
  const float am = fmaxf(red[0], 1e-20f);
  const float inv = 127.f / am;
  if (t == 0) sx[row] = am * (1.f / 127.f);
  int* xq32 = (int*)(xq + (size_t)row * K);
  #pragma unroll
  for (int c = 0; c < 4; ++c) {
    int q0 = min(127, max(-127, __float2int_rn(v[c].x * inv)));
    int q1 = min(127, max(-127, __float2int_rn(v[c].y * inv)));
    int q2 = min(127, max(-127, __float2int_rn(v[c].z * inv)));
    int q3 = min(127, max(-127, __float2int_rn(v[c].w * inv)));
    xq32[c * 256 + t] = (q0 & 255) | ((q1 & 255) << 8) |
                        ((q2 & 255) << 16) | ((q3 & 255) << 24);
  }
}

// ---- 256x256 int8 GEMM, ring-4 LDS, 2-phase-per-tile fine interleave ----
// Per phase: {6 ds_read_b128 (this substep) || 2 global_load_lds (tile t+3)}
//   -> s_barrier -> lgkmcnt(0) -> setprio(1) + 8 MFMA + setprio(0) -> s_barrier
// vmcnt(8) once per tile BEFORE the phase-1 barrier (tile t+1 landed for all
// waves after that barrier); epilogue drains 8 -> 4 -> 0.
__global__ __launch_bounds__(512, 2) void gemm_i8_kernel(const signed char* __restrict__ aq,
                                                         const signed char* __restrict__ wq,
                                                         const float* __restrict__ sx,
                                                         const float* __restrict__ sw,
                                                         float* __restrict__ out) {
  extern __shared__ signed char smem[];            // 131072 B
  signed char* lsA = smem;                          // 4 bufs x 16 KB
  signed char* lsB = smem + 4 * TILE_BYTES;         // 4 bufs x 16 KB

  const int tid = threadIdx.x;
  const int w = tid >> 6;          // wave 0..7
  const int l = tid & 63;

  // XCD-aware swizzle (bijective: 2752 % 8 == 0).
  const int bid = blockIdx.x;
  const int wg = (bid & 7) * (NWG / 8) + (bid >> 3);
  const int mt = wg / NT_N;
  const int nt = wg % NT_N;
  const int m0 = mt * BM, n0 = nt * BN;

  // Staging: waves 0..3 stage A, waves 4..7 stage B; 4 chunks (1KB) per thread.
  const bool stA = (w < 4);
  const signed char* src[4];
  int loff[4];
  #pragma unroll
  for (int c = 0; c < 4; ++c) {
    const int q = (w & 3) * 4 + c;
    const int row = (q & 3) * 64 + l;
    const int s = q >> 2;
    const signed char* base = stA ? (aq + (size_t)(m0 + row) * K)
                                  : (wq + (size_t)(n0 + row) * K);
    src[c] = base + s * 16;
    loff[c] = q * 1024;            // wave-uniform dest base; HW adds lane*16
  }

#define STAGE_HALF(tile, h)                                                   \
  {                                                                           \
    signed char* lbase = (stA ? lsA : lsB) + ((tile) & 3) * TILE_BYTES;       \
    const int koff = (tile) * BK;                                             \
    gload_lds16(src[2 * (h)] + koff, lbase + loff[2 * (h)]);                  \
    gload_lds16(src[2 * (h) + 1] + koff, lbase + loff[2 * (h) + 1]);          \
  }

#define STAGE_FULL(tile) STAGE_HALF(tile, 0) STAGE_HALF(tile, 1)

  // Wave output: 128x64 at (wm*128, wn*64); 4x2 frags of 32x32.
  const int wm = w >> 2, wn = w & 3;
  const int aBase = (l >> 5) * 4096 + (wm * 128 + (l & 31)) * 16;
  const int bBase = (l >> 5) * 4096 + (wn * 64 + (l & 31)) * 16;

  int32x16 acc[4][2] = {};
  int32x4 af[4], bf[2];

#define DS_LOADS(tile, ks)                                                    \
  {                                                                           \
    const signed char* pA = lsA + ((tile) & 3) * TILE_BYTES;                  \
    const signed char* pB = lsB + ((tile) & 3) * TILE_BYTES;                  \
    const int ko = (ks) * 8192;                                               \
    bf[0] = *(const int32x4*)(pB + bBase + ko);                               \
    bf[1] = *(const int32x4*)(pB + bBase + ko + 512);                         \
    af[0] = *(const int32x4*)(pA + aBase + ko);                               \
    af[1] = *(const int32x4*)(pA + aBase + ko + 512);                         \
    af[2] = *(const int32x4*)(pA + aBase + ko + 1024);                        \
    af[3] = *(const int32x4*)(pA + aBase + ko + 1536);                        \
  }

#define LGKM0()                                          \
  asm volatile("s_waitcnt lgkmcnt(0)" ::: "memory");     \
  __builtin_amdgcn_sched_barrier(0);

#define MFMA8()                                                               \
  __builtin_amdgcn_s_setprio(1);                                              \
  {                                                                           \
    _Pragma("unroll")                                                         \
    for (int i = 0; i < 4; ++i) {                                             \
      acc[i][0] = __builtin_amdgcn_mfma_i32_32x32x32_i8(af[i], bf[0],         \
                                                        acc[i][0], 0, 0, 0);  \
      acc[i][1] = __builtin_amdgcn_mfma_i32_32x32x32_i8(af[i], bf[1],         \
                                                        acc[i][1], 0, 0, 0);  \
    }                                                                         \
  }                                                                           \
  __builtin_amdgcn_s_setprio(0);

#define BAR() __builtin_amdgcn_s_barrier();

  // Prologue: stage tiles 0..2 (12 loads/thread); ensure tile 0 landed.
  STAGE_FULL(0) STAGE_FULL(1) STAGE_FULL(2)
  asm volatile("s_waitcnt vmcnt(8)" ::: "memory");
  BAR()

  // Main loop: t = 0..59, ring indices fold via unroll 4.
  #pragma unroll 4
  for (int t = 0; t < 60; ++t) {
    // phase 0 (ks = 0)
    DS_LOADS(t, 0)
    STAGE_HALF(t + 3, 0)
    BAR()
    LGKM0()
    MFMA8()
    BAR()
    // phase 1 (ks = 1)
    DS_LOADS(t, 1)
    STAGE_HALF(t + 3, 1)
    asm volatile("s_waitcnt vmcnt(8)" ::: "memory");  // tile t+1 landed after BAR
    BAR()
    LGKM0()
    MFMA8()
    BAR()
  }
  // t = 60: last staging tile (63), vmcnt(8)
  DS_LOADS(60, 0) STAGE_HALF(63, 0) BAR() LGKM0() MFMA8() BAR()
  DS_LOADS(60, 1) STAGE_HALF(63, 1)
  asm volatile("s_waitcnt vmcnt(8)" ::: "memory");
  BAR() LGKM0() MFMA8() BAR()
  // t = 61: no staging, drain to 4 (tile 62 landed)
  DS_LOADS(61, 0) BAR() LGKM0() MFMA8() BAR()
  DS_LOADS(61, 1)
  asm volatile("s_waitcnt vmcnt(4)" ::: "memory");
  BAR() LGKM0() MFMA8() BAR()
  // t = 62: drain to 0 (tile 63 landed)
  DS_LOADS(62, 0) BAR() LGKM0() MFMA8() BAR()
  DS_LOADS(62, 1)
  asm volatile("s_waitcnt vmcnt(0)" ::: "memory");
  BAR() LGKM0() MFMA8() BAR()
  // t = 63: final tile
  DS_LOADS(63, 0) BAR() LGKM0() MFMA8() BAR()
  DS_LOADS(63, 1) BAR() LGKM0() MFMA8()

  // Epilogue: dequant + store.
  // 32x32 C/D map: col = lane&31, row = (r&3) + 8*(r>>2) + 4*(lane>>5).
  const int col = l & 31;
  const int rbase = (l >> 5) * 4;
  float swv[2];
  #pragma unroll
  for (int fj = 0; fj < 2; ++fj) swv[fj] = sw[n0 + wn * 64 + fj * 32 + col];
  #pragma unroll
  for (int fi = 0; fi < 4; ++fi) {
    #pragma unroll
    for (int r = 0; r < 16; ++r) {
      const int row = (r & 3) + 8 * (r >> 2) + rbase;
      const int grow = m0 + wm * 128 + fi * 32 + row;
      const float sxv = sx[grow];
      float* orow = out + (size_t)grow * N + n0 + wn * 64 + col;
      #pragma unroll
      for (int fj = 0; fj < 2; ++fj) {
        orow[fj * 32] = (float)acc[fi][fj][r] * sxv * swv[fj];
      }
    }
  }
}

extern "C" void kernel_launch(void* const* d_in, const int* in_sizes, int n_in,
                              void* d_out, int out_size, void* d_ws, size_t ws_size,
                              hipStream_t stream) {
  const float* x = (const float*)d_in[0];
  const int* w32 = (const int*)d_in[1];
  const float* wscale = (const float*)d_in[2];
  float* out = (float*)d_out;

  signed char* xq = (signed char*)d_ws;
  signed char* wq = xq + (size_t)M * K;
  float* sx = (float*)(wq + (size_t)N * K);

  pack_w_kernel<<<(N * K / 4 + 255) / 256, 256, 0, stream>>>(w32, wq);
  quant_x_kernel<<<M, 256, 0, stream>>>(x, xq, sx);
  gemm_i8_kernel<<<NWG, 512, 131072, stream>>>(xq, wq, sx, wscale, out);
}